// Round 3
// baseline (229.880 us; speedup 1.0000x reference)
//
#include <hip/hip_runtime.h>

#define B 32
#define S 3136
#define C 256
#define W 98            // 32-bit words per channel: 98*32 = 3136
#define THRESH 1568     // cnt >= S*0.5 -> percent >= SIMILARITY -> kill
#define TC 8            // channels per k_mask block
#define NCHUNK 49       // spatial chunks for mean partials (64 rows each)

// ---- pass 1a: per-chunk partial sums, float4, no atomics ----
__global__ __launch_bounds__(256) void k_mean_part(const float* __restrict__ x,
                                                   float* __restrict__ partial) {
    const int b = blockIdx.x;         // 0..31
    const int chunk = blockIdx.y;     // 0..48 (64 rows each)
    const int c4 = threadIdx.x & 63;  // float4 group within channel dim
    const int r  = threadIdx.x >> 6;  // 0..3
    const float4* p = (const float4*)(x + ((size_t)b * S + (size_t)chunk * 64 + r) * C) + c4;
    float4 sum = make_float4(0.f, 0.f, 0.f, 0.f);
#pragma unroll
    for (int k = 0; k < 16; ++k) {    // rows r, r+4, ..., r+60
        float4 v = p[(size_t)k * 4 * (C / 4)];
        sum.x += v.x; sum.y += v.y; sum.z += v.z; sum.w += v.w;
    }
    __shared__ float4 sm[256];
    sm[threadIdx.x] = sum;
    __syncthreads();
    if (r == 0) {
        float4 a = sm[c4], b2 = sm[c4 + 64], c_ = sm[c4 + 128], d = sm[c4 + 192];
        float4 t;
        t.x = a.x + b2.x + c_.x + d.x;
        t.y = a.y + b2.y + c_.y + d.y;
        t.z = a.z + b2.z + c_.z + d.z;
        t.w = a.w + b2.w + c_.w + d.w;
        ((float4*)(partial + ((size_t)b * NCHUNK + chunk) * C))[c4] = t;
    }
}

// ---- pass 1b: reduce partials -> mean ----
__global__ __launch_bounds__(256) void k_meanred(const float* __restrict__ partial,
                                                 float* __restrict__ mean) {
    const int b = blockIdx.x;
    const int c = threadIdx.x;
    float sum = 0.f;
#pragma unroll
    for (int k = 0; k < NCHUNK; ++k)
        sum += partial[((size_t)b * NCHUNK + k) * C + c];
    mean[b * C + c] = sum * (1.0f / (float)S);
}

// ---- pass 2: bit-pack live = (x > mean), float4, uint4 store ----
__global__ __launch_bounds__(256) void k_bits(const float* __restrict__ x,
                                              const float* __restrict__ mean,
                                              unsigned int* __restrict__ bits) {
    const int b = blockIdx.x;                           // 0..31
    const int w = blockIdx.y * 4 + (threadIdx.x >> 6);  // word index, wave-uniform
    if (w >= W) return;
    const int c4 = threadIdx.x & 63;
    const float4 m = ((const float4*)(mean + b * C))[c4];
    const float4* p = (const float4*)(x + ((size_t)b * S + (size_t)w * 32) * C) + c4;
    unsigned int w0 = 0, w1 = 0, w2 = 0, w3 = 0;
#pragma unroll
    for (int k = 0; k < 32; ++k) {
        float4 v = p[(size_t)k * (C / 4)];
        w0 |= (v.x > m.x) ? (1u << k) : 0u;
        w1 |= (v.y > m.y) ? (1u << k) : 0u;
        w2 |= (v.z > m.z) ? (1u << k) : 0u;
        w3 |= (v.w > m.w) ? (1u << k) : 0u;
    }
    uint4 out; out.x = w0; out.y = w1; out.z = w2; out.w = w3;
    ((uint4*)(bits + ((size_t)b * W + w) * C))[c4] = out;
}

// ---- pass 3: pairwise co-live via popcount ----
// Group words bb[w*C + c0 + t] have thread-invariant addresses -> SMEM
// s_load into SGPRs; inner loop is pure VALU (v_and sgpr + v_bcnt + v_add).
// No LDS in the hot loop (R2's version serialized on the LDS pipe).
__global__ __launch_bounds__(256) void k_mask(const unsigned int* __restrict__ bits,
                                              float* __restrict__ rmask) {
    const int b  = blockIdx.x;          // 0..31
    const int c0 = blockIdx.y * TC;     // channel group this block decides
    const int j  = threadIdx.x;         // partner channel
    const unsigned int* bb = bits + (size_t)b * (W * C);

    unsigned int cnt[TC];
#pragma unroll
    for (int t = 0; t < TC; ++t) cnt[t] = 0;

#pragma unroll 2
    for (int w = 0; w < W; ++w) {
        const unsigned int bj = bb[(size_t)w * C + j];        // coalesced vload
        const unsigned int* bc = bb + (size_t)w * C + c0;     // uniform -> s_load
#pragma unroll
        for (int t = 0; t < TC; ++t)
            cnt[t] += __popc(bj & bc[t]);
    }

    __shared__ unsigned int km;
    if (j == 0) km = 0u;
    __syncthreads();

    unsigned int kill = 0;
#pragma unroll
    for (int t = 0; t < TC; ++t)
        if ((c0 + t) != j && cnt[t] >= THRESH) kill |= (1u << t);
    if (kill) atomicOr(&km, kill);
    __syncthreads();

    if (j < TC)
        rmask[b * C + c0 + j] = ((km >> j) & 1u) ? 0.0f : 1.0f;
}

// ---- pass 4: out = x * mask; 4 rows per thread, mask hoisted ----
__global__ __launch_bounds__(256) void k_apply(const float* __restrict__ x,
                                               const float* __restrict__ rmask,
                                               float* __restrict__ out) {
    const size_t t = (size_t)blockIdx.x * 256 + threadIdx.x;
    const int c4 = (int)(t & 63);
    const size_t q = t >> 6;                 // row-quad index, 0 .. B*S/4-1
    const int b = (int)(q / (S / 4));
    const float4 m = ((const float4*)rmask)[b * (C / 4) + c4];
    const float4* px = (const float4*)x + q * 4 * (C / 4) + c4;
    float4* po = (float4*)out + q * 4 * (C / 4) + c4;
#pragma unroll
    for (int k = 0; k < 4; ++k) {
        float4 v = px[(size_t)k * (C / 4)];
        v.x *= m.x; v.y *= m.y; v.z *= m.z; v.w *= m.w;
        po[(size_t)k * (C / 4)] = v;
    }
}

extern "C" void kernel_launch(void* const* d_in, const int* in_sizes, int n_in,
                              void* d_out, int out_size, void* d_ws, size_t ws_size,
                              hipStream_t stream) {
    const float* x = (const float*)d_in[0];
    float* out = (float*)d_out;

    // workspace layout (no init required — every word fully overwritten)
    float* partial     = (float*)d_ws;                                   // 1.6 MB
    float* mean        = partial + (size_t)B * NCHUNK * C;               // 32 KB
    unsigned int* bits = (unsigned int*)(mean + (size_t)B * C);          // 3.2 MB
    float* rmask       = (float*)(bits + (size_t)B * W * C);             // 32 KB

    k_mean_part<<<dim3(B, NCHUNK), 256, 0, stream>>>(x, partial);
    k_meanred  <<<B, 256, 0, stream>>>(partial, mean);
    k_bits     <<<dim3(B, (W + 3) / 4), 256, 0, stream>>>(x, mean, bits);
    k_mask     <<<dim3(B, C / TC), 256, 0, stream>>>(bits, rmask);

    const size_t nthreads = (size_t)B * (S / 4) * (C / 4);  // 1,605,632
    k_apply<<<(unsigned)(nthreads / 256), 256, 0, stream>>>(x, rmask, out);
}

// Round 4
// 215.160 us; speedup vs baseline: 1.0684x; 1.0684x over previous
//
#include <hip/hip_runtime.h>

#define B 32
#define S 3136
#define C 256
#define W 98            // 32-bit words per channel: 98*32 = 3136
#define THRESH 1568     // cnt >= S*0.5 -> percent >= SIMILARITY -> kill
#define TC 8            // channels per k_mask block
#define NCHUNK 49       // spatial chunks for mean partials (64 rows each)

// ---- pass 1: per-chunk partial sums, float4, no atomics ----
__global__ __launch_bounds__(256) void k_mean_part(const float* __restrict__ x,
                                                   float* __restrict__ partial) {
    const int b = blockIdx.x;         // 0..31
    const int chunk = blockIdx.y;     // 0..48 (64 rows each)
    const int c4 = threadIdx.x & 63;  // float4 group within channel dim
    const int r  = threadIdx.x >> 6;  // 0..3
    const float4* p = (const float4*)(x + ((size_t)b * S + (size_t)chunk * 64 + r) * C) + c4;
    float4 sum = make_float4(0.f, 0.f, 0.f, 0.f);
#pragma unroll
    for (int k = 0; k < 16; ++k) {    // rows r, r+4, ..., r+60
        float4 v = p[(size_t)k * 4 * (C / 4)];
        sum.x += v.x; sum.y += v.y; sum.z += v.z; sum.w += v.w;
    }
    __shared__ float4 sm[256];
    sm[threadIdx.x] = sum;
    __syncthreads();
    if (r == 0) {
        float4 a = sm[c4], b2 = sm[c4 + 64], c_ = sm[c4 + 128], d = sm[c4 + 192];
        float4 t;
        t.x = a.x + b2.x + c_.x + d.x;
        t.y = a.y + b2.y + c_.y + d.y;
        t.z = a.z + b2.z + c_.z + d.z;
        t.w = a.w + b2.w + c_.w + d.w;
        ((float4*)(partial + ((size_t)b * NCHUNK + chunk) * C))[c4] = t;
    }
}

// ---- pass 2: reduce partials -> mean (per block), bit-pack live, AND copy
// out = x (x is already in registers; saves k_apply's full re-read of x).
__global__ __launch_bounds__(256) void k_bits_copy(const float* __restrict__ x,
                                                   const float* __restrict__ partial,
                                                   unsigned int* __restrict__ bits,
                                                   float* __restrict__ out) {
    const int b = blockIdx.x;                           // 0..31
    const int w = blockIdx.y * 4 + (threadIdx.x >> 6);  // word index, wave-uniform
    const int c4 = threadIdx.x & 63;

    // inline mean reduction for this thread's 4 channels (L2-resident partials)
    const float4* pp = (const float4*)(partial + (size_t)b * NCHUNK * C) + c4;
    float4 msum = make_float4(0.f, 0.f, 0.f, 0.f);
#pragma unroll
    for (int k = 0; k < NCHUNK; ++k) {
        float4 v = pp[(size_t)k * (C / 4)];
        msum.x += v.x; msum.y += v.y; msum.z += v.z; msum.w += v.w;
    }
    const float inv = 1.0f / (float)S;
    float4 m; m.x = msum.x * inv; m.y = msum.y * inv; m.z = msum.z * inv; m.w = msum.w * inv;

    if (w >= W) return;   // tail waves of last word-group

    const size_t rowbase = ((size_t)b * S + (size_t)w * 32) * C;
    const float4* p  = (const float4*)(x + rowbase) + c4;
    float4*       po = (float4*)(out + rowbase) + c4;
    unsigned int w0 = 0, w1 = 0, w2 = 0, w3 = 0;
#pragma unroll
    for (int k = 0; k < 32; ++k) {
        float4 v = p[(size_t)k * (C / 4)];
        po[(size_t)k * (C / 4)] = v;                    // out = x
        w0 |= (v.x > m.x) ? (1u << k) : 0u;
        w1 |= (v.y > m.y) ? (1u << k) : 0u;
        w2 |= (v.z > m.z) ? (1u << k) : 0u;
        w3 |= (v.w > m.w) ? (1u << k) : 0u;
    }
    uint4 ob; ob.x = w0; ob.y = w1; ob.z = w2; ob.w = w3;
    ((uint4*)(bits + ((size_t)b * W + w) * C))[c4] = ob;
}

// ---- pass 3: pairwise co-live via popcount (SGPR-broadcast group words) ----
__global__ __launch_bounds__(256) void k_mask(const unsigned int* __restrict__ bits,
                                              float* __restrict__ rmask) {
    const int b  = blockIdx.x;          // 0..31
    const int c0 = blockIdx.y * TC;     // channel group this block decides
    const int j  = threadIdx.x;         // partner channel
    const unsigned int* bb = bits + (size_t)b * (W * C);

    unsigned int cnt[TC];
#pragma unroll
    for (int t = 0; t < TC; ++t) cnt[t] = 0;

#pragma unroll 2
    for (int w = 0; w < W; ++w) {
        const unsigned int bj = bb[(size_t)w * C + j];        // coalesced vload
        const unsigned int* bc = bb + (size_t)w * C + c0;     // uniform -> s_load
#pragma unroll
        for (int t = 0; t < TC; ++t)
            cnt[t] += __popc(bj & bc[t]);
    }

    __shared__ unsigned int km;
    if (j == 0) km = 0u;
    __syncthreads();

    unsigned int kill = 0;
#pragma unroll
    for (int t = 0; t < TC; ++t)
        if ((c0 + t) != j && cnt[t] >= THRESH) kill |= (1u << t);
    if (kill) atomicOr(&km, kill);
    __syncthreads();

    if (j < TC)
        rmask[b * C + c0 + j] = ((km >> j) & 1u) ? 0.0f : 1.0f;
}

// ---- pass 4: zero killed channels of out (out already holds x).
// All-live channels (the overwhelmingly common case): mask load + exit.
__global__ __launch_bounds__(256) void k_fixup(const float* __restrict__ rmask,
                                               float* __restrict__ out) {
    const int b = blockIdx.x;         // 0..31
    const int chunk = blockIdx.y;     // 0..48, 64 rows each
    const int c4 = threadIdx.x & 63;
    const int r  = threadIdx.x >> 6;
    const float4 m = ((const float4*)rmask)[b * (C / 4) + c4];
    if (m.x + m.y + m.z + m.w == 4.0f) return;   // all live -> nothing to do

    float* po = out + ((size_t)b * S + (size_t)chunk * 64 + r) * C + c4 * 4;
#pragma unroll
    for (int k = 0; k < 16; ++k) {               // rows r, r+4, ..., r+60
        float* q = po + (size_t)k * 4 * C;
        if (m.x == 0.f) q[0] = 0.f;
        if (m.y == 0.f) q[1] = 0.f;
        if (m.z == 0.f) q[2] = 0.f;
        if (m.w == 0.f) q[3] = 0.f;
    }
}

extern "C" void kernel_launch(void* const* d_in, const int* in_sizes, int n_in,
                              void* d_out, int out_size, void* d_ws, size_t ws_size,
                              hipStream_t stream) {
    const float* x = (const float*)d_in[0];
    float* out = (float*)d_out;

    // workspace layout (no init required — every word fully overwritten
    // before first read, with a kernel boundary between write and read)
    float* partial     = (float*)d_ws;                                   // 1.6 MB
    unsigned int* bits = (unsigned int*)(partial + (size_t)B * NCHUNK * C); // 3.2 MB
    float* rmask       = (float*)(bits + (size_t)B * W * C);             // 32 KB

    k_mean_part<<<dim3(B, NCHUNK),      256, 0, stream>>>(x, partial);
    k_bits_copy<<<dim3(B, (W + 3) / 4), 256, 0, stream>>>(x, partial, bits, out);
    k_mask     <<<dim3(B, C / TC),      256, 0, stream>>>(bits, rmask);
    k_fixup    <<<dim3(B, NCHUNK),      256, 0, stream>>>(rmask, out);
}

// Round 5
// 213.659 us; speedup vs baseline: 1.0759x; 1.0070x over previous
//
#include <hip/hip_runtime.h>

#define B 32
#define S 3136
#define C 256
#define W 98            // 32-bit words per channel: 98*32 = 3136
#define THRESH 1568     // cnt >= S*0.5 -> percent >= SIMILARITY -> kill
#define TC 8            // channels per k_mask block
#define NCHUNK 49       // spatial chunks for mean partials (64 rows each)

// ---- pass 1: per-chunk partial sums, float4, no atomics ----
__global__ __launch_bounds__(256) void k_mean_part(const float* __restrict__ x,
                                                   float* __restrict__ partial) {
    const int b = blockIdx.x;         // 0..31
    const int chunk = blockIdx.y;     // 0..48 (64 rows each)
    const int c4 = threadIdx.x & 63;  // float4 group within channel dim
    const int r  = threadIdx.x >> 6;  // 0..3
    const float4* p = (const float4*)(x + ((size_t)b * S + (size_t)chunk * 64 + r) * C) + c4;
    float4 sum = make_float4(0.f, 0.f, 0.f, 0.f);
#pragma unroll
    for (int k = 0; k < 16; ++k) {    // rows r, r+4, ..., r+60
        float4 v = p[(size_t)k * 4 * (C / 4)];
        sum.x += v.x; sum.y += v.y; sum.z += v.z; sum.w += v.w;
    }
    __shared__ float4 sm[256];
    sm[threadIdx.x] = sum;
    __syncthreads();
    if (r == 0) {
        float4 a = sm[c4], b2 = sm[c4 + 64], c_ = sm[c4 + 128], d = sm[c4 + 192];
        float4 t;
        t.x = a.x + b2.x + c_.x + d.x;
        t.y = a.y + b2.y + c_.y + d.y;
        t.z = a.z + b2.z + c_.z + d.z;
        t.w = a.w + b2.w + c_.w + d.w;
        ((float4*)(partial + ((size_t)b * NCHUNK + chunk) * C))[c4] = t;
    }
}

// ---- pass 2: reduce partials -> mean (per block), bit-pack live, AND copy
// out = x (x already in registers; avoids a third full pass over x).
__global__ __launch_bounds__(256) void k_bits_copy(const float* __restrict__ x,
                                                   const float* __restrict__ partial,
                                                   unsigned int* __restrict__ bits,
                                                   float* __restrict__ out) {
    const int b = blockIdx.x;                           // 0..31
    const int w = blockIdx.y * 4 + (threadIdx.x >> 6);  // word index, wave-uniform
    const int c4 = threadIdx.x & 63;

    // inline mean reduction for this thread's 4 channels (L2-resident partials)
    const float4* pp = (const float4*)(partial + (size_t)b * NCHUNK * C) + c4;
    float4 msum = make_float4(0.f, 0.f, 0.f, 0.f);
#pragma unroll
    for (int k = 0; k < NCHUNK; ++k) {
        float4 v = pp[(size_t)k * (C / 4)];
        msum.x += v.x; msum.y += v.y; msum.z += v.z; msum.w += v.w;
    }
    const float inv = 1.0f / (float)S;
    float4 m; m.x = msum.x * inv; m.y = msum.y * inv; m.z = msum.z * inv; m.w = msum.w * inv;

    if (w >= W) return;   // tail waves of last word-group

    const size_t rowbase = ((size_t)b * S + (size_t)w * 32) * C;
    const float4* p  = (const float4*)(x + rowbase) + c4;
    float4*       po = (float4*)(out + rowbase) + c4;
    unsigned int w0 = 0, w1 = 0, w2 = 0, w3 = 0;
#pragma unroll
    for (int k = 0; k < 32; ++k) {
        float4 v = p[(size_t)k * (C / 4)];
        po[(size_t)k * (C / 4)] = v;                    // out = x
        w0 |= (v.x > m.x) ? (1u << k) : 0u;
        w1 |= (v.y > m.y) ? (1u << k) : 0u;
        w2 |= (v.z > m.z) ? (1u << k) : 0u;
        w3 |= (v.w > m.w) ? (1u << k) : 0u;
    }
    uint4 ob; ob.x = w0; ob.y = w1; ob.z = w2; ob.w = w3;
    ((uint4*)(bits + ((size_t)b * W + w) * C))[c4] = ob;
}

// ---- pass 3: pairwise co-live via popcount + in-place fixup of out ----
// Block (b, c0-group) decides 8 channels; if any are killed it zeroes those
// spatial columns of out itself (out already holds x). Common case: no kill,
// no writes at all. rmask buffer and the 4th dispatch are gone.
__global__ __launch_bounds__(256) void k_mask_fix(const unsigned int* __restrict__ bits,
                                                  float* __restrict__ out) {
    const int b  = blockIdx.x;          // 0..31
    const int c0 = blockIdx.y * TC;     // channel group this block decides
    const int j  = threadIdx.x;         // partner channel
    const unsigned int* bb = bits + (size_t)b * (W * C);

    unsigned int cnt[TC];
#pragma unroll
    for (int t = 0; t < TC; ++t) cnt[t] = 0;

#pragma unroll 2
    for (int w = 0; w < W; ++w) {
        const unsigned int bj = bb[(size_t)w * C + j];        // coalesced vload
        const unsigned int* bc = bb + (size_t)w * C + c0;     // uniform -> s_load
#pragma unroll
        for (int t = 0; t < TC; ++t)
            cnt[t] += __popc(bj & bc[t]);
    }

    __shared__ unsigned int km;
    if (j == 0) km = 0u;
    __syncthreads();

    unsigned int kill = 0;
#pragma unroll
    for (int t = 0; t < TC; ++t)
        if ((c0 + t) != j && cnt[t] >= THRESH) kill |= (1u << t);
    if (kill) atomicOr(&km, kill);
    __syncthreads();

    const unsigned int k2 = km;
    if (k2 == 0u) return;               // all 8 channels live -> done (fast path)

    // zero killed channels: thread j covers rows j, j+256, ...
#pragma unroll
    for (int t = 0; t < TC; ++t) {
        if ((k2 >> t) & 1u) {
            float* col = out + (size_t)b * S * C + (c0 + t);
            for (int row = j; row < S; row += 256)
                col[(size_t)row * C] = 0.0f;
        }
    }
}

extern "C" void kernel_launch(void* const* d_in, const int* in_sizes, int n_in,
                              void* d_out, int out_size, void* d_ws, size_t ws_size,
                              hipStream_t stream) {
    const float* x = (const float*)d_in[0];
    float* out = (float*)d_out;

    // workspace layout (no init required — every word fully overwritten
    // before first read, with a kernel boundary between write and read)
    float* partial     = (float*)d_ws;                                      // 1.6 MB
    unsigned int* bits = (unsigned int*)(partial + (size_t)B * NCHUNK * C); // 3.2 MB

    k_mean_part<<<dim3(B, NCHUNK),      256, 0, stream>>>(x, partial);
    k_bits_copy<<<dim3(B, (W + 3) / 4), 256, 0, stream>>>(x, partial, bits, out);
    k_mask_fix <<<dim3(B, C / TC),      256, 0, stream>>>(bits, out);
}